// Round 7
// baseline (380.936 us; speedup 1.0000x reference)
//
#include <hip/hip_runtime.h>
#include <cmath>

#define SRATE 16000
#define WIN   400
#define HOP   160
#define NFFT  512
#define NBIN  257          // NFFT/2+1
#define NMELS 40
#define NMFCC 13
#define BB    64
#define LL    160000
#define NF    998          // (L-WIN)/HOP + 1

#define PI_D 3.14159265358979323846

// workspace layout (floats)
#define WS_WINDOW 0                    // 400 (pre-scaled by 0.5: folds rfft-untangle factor)
#define WS_W1     400                  // 64 x float2 = 128   (W_256^l)
#define WS_STW    528                  // 6 stages x 64 x float2 = 768
#define WS_UNTC   1296                 // 64 x float4 = 256 (permuted untangle cos)
#define WS_UNTS   1552                 // 64 x float4 = 256 (permuted untangle -sin)
#define WS_SM     1808                 // 64 (filter support start bin)
#define WS_FBW    1872                 // 9 jc x 64 lanes x 4 = 2304 (mel weights)
#define WS_MTT    4176                 // 39 x 40 = 1560 (fused DCT+delta, TRANSPOSED [i][n])
#define WS_TOTAL  (WS_MTT + 1560)      // 5736 floats

using v2f = __attribute__((ext_vector_type(2))) float;

__device__ __forceinline__ int brev6(int v) { return (int)(__brev((unsigned)v) >> 26); }
__device__ __forceinline__ v2f splat(float s) { v2f r; r.x = s; r.y = s; return r; }

template<int CTRL>
__device__ __forceinline__ float dppf(float x) {
    return __int_as_float(__builtin_amdgcn_mov_dpp(__float_as_int(x), CTRL, 0xF, 0xF, true));
}
template<int CTRL>
__device__ __forceinline__ v2f dpp2(v2f v) {
    v2f r; r.x = dppf<CTRL>(v.x); r.y = dppf<CTRL>(v.y); return r;
}
__device__ __forceinline__ v2f sfx2(v2f v, int m) {
    v2f r; r.x = __shfl_xor(v.x, m, 64); r.y = __shfl_xor(v.y, m, 64); return r;
}
__device__ __forceinline__ v2f sfl2(v2f v, int src) {
    v2f r; r.x = __shfl(v.x, src, 64); r.y = __shfl(v.y, src, 64); return r;
}

// DPP controls: quad_perm xor1 = [1,0,3,2] = 0xB1; xor2 = [2,3,0,1] = 0x4E;
// row_ror:8 = 0x128 (== xor8 within each 16-lane row).
#define DPP_XOR1 0xB1
#define DPP_XOR2 0x4E
#define DPP_XOR8 0x128

// ---- gfx950 permlane swaps: xor16/xor32 butterflies on the VALU pipe ----
#if __has_builtin(__builtin_amdgcn_permlane32_swap) && __has_builtin(__builtin_amdgcn_permlane16_swap)
#define PLSWAP(FN, Z, A, Bv)                                                          \
    {                                                                                 \
        auto _r0 = FN(__float_as_int((Z).x), __float_as_int((Z).x), false, false);    \
        auto _r1 = FN(__float_as_int((Z).y), __float_as_int((Z).y), false, false);    \
        (A).x = __int_as_float(_r0[0]); (Bv).x = __int_as_float(_r0[1]);              \
        (A).y = __int_as_float(_r1[0]); (Bv).y = __int_as_float(_r1[1]);              \
    }
#define PL32(Z, A, Bv) PLSWAP(__builtin_amdgcn_permlane32_swap, Z, A, Bv)
#define PL16(Z, A, Bv) PLSWAP(__builtin_amdgcn_permlane16_swap, Z, A, Bv)
#else
#define PL32(Z, A, Bv) { (A) = sfx2((Z), 32); (Bv) = (Z); }
#define PL16(Z, A, Bv) { (A) = sfx2((Z), 16); (Bv) = (Z); }
#endif

// ---------------------------------------------------------------------------
// Init kernel (64 blocks): recompute constant tables every launch.
// ---------------------------------------------------------------------------
__global__ void init_tables(float* __restrict__ ws) {
    __shared__ double bins[NMELS + 2];
    const int tid = threadIdx.x;
    const int gid = blockIdx.x * 256 + tid;
    const int gstr = gridDim.x * 256;

    if (tid < NMELS + 2) {
        double high_mel = 2595.0 * log10(1.0 + ((double)SRATE / 2.0) / 700.0);
        double step = high_mel / (double)(NMELS + 1);
        double mel = (tid == NMELS + 1) ? high_mel : (double)tid * step;
        double hz = 700.0 * (pow(10.0, mel / 2595.0) - 1.0);
        bins[tid] = floor((double)(NFFT + 1) * hz / (double)SRATE);
    }
    __syncthreads();

    for (int i = gid; i < WIN; i += gstr)
        ws[WS_WINDOW + i] = (float)(0.5 * (0.54 - 0.46 * cos(2.0 * PI_D * (double)i / (double)WIN)));

    if (gid < 64) {
        double ang = -2.0 * PI_D * (double)gid / 256.0;
        ws[WS_W1 + 2 * gid]     = (float)cos(ang);
        ws[WS_W1 + 2 * gid + 1] = (float)sin(ang);
    }

    for (int i = gid; i < 6 * 64; i += gstr) {
        int st = i >> 6, lane = i & 63;
        int h = 32 >> st;
        double cr = 1.0, ci = 0.0;
        if (lane & h) {
            double ang = -PI_D * (double)(lane & (h - 1)) / (double)h;
            cr = cos(ang); ci = sin(ang);
        }
        ws[WS_STW + st * 128 + 2 * lane]     = (float)cr;
        ws[WS_STW + st * 128 + 2 * lane + 1] = (float)ci;
    }

    for (int i = gid; i < 256; i += gstr) {
        int lane = i >> 2, k1 = i & 3;
        int m = k1 + 4 * brev6(lane);
        double ang = 2.0 * PI_D * (double)m / 512.0;
        ws[WS_UNTC + 4 * lane + k1] = (float)cos(ang);
        ws[WS_UNTS + 4 * lane + k1] = (float)(-sin(ang));
    }

    for (int i = gid; i < 64; i += gstr)
        ws[WS_SM + i] = (i < NMELS) ? (float)bins[i] : 0.0f;

    for (int i = gid; i < 9 * 256; i += gstr) {
        int jc = i >> 8, r = (i >> 2) & 63, d = i & 3;
        int j = jc * 4 + d;
        double v = 0.0;
        if (r < NMELS) {
            double flo = bins[r], fc = bins[r + 1], fhi = bins[r + 2];
            int k = (int)flo + j;
            if (k < (int)fc)        v = ((double)k - flo) / (fc - flo);
            else if (k < (int)fhi)  v = (fhi - (double)k) / (fhi - fc);
        }
        ws[WS_FBW + i] = (float)v;
    }

    for (int t = gid; t < 39 * 40; t += gstr) {
        int i = t / 40, n = t % 40;
        auto dctf = [&](int c) -> double {
            if (c < 0 || c > 39) return 0.0;
            double sc = (c == 0) ? sqrt(1.0 / 40.0) : sqrt(2.0 / 40.0);
            return sc * cos(PI_D * (double)c * (2.0 * n + 1.0) / 80.0);
        };
        auto d1f = [&](int c) -> double {
            if (c < 1 || c > 38) return 0.0;
            return 0.5 * (dctf(c + 1) - dctf(c - 1));
        };
        double v;
        if (i < 13)       v = dctf(i);
        else if (i < 26)  v = d1f(i - 13);
        else { int c = i - 26; v = (c >= 1 && c <= 38) ? 0.5 * (d1f(c + 1) - d1f(c - 1)) : 0.0; }
        ws[WS_MTT + t] = (float)v;
    }
}

// ---------------------------------------------------------------------------
// Main kernel: one WAVE per FOUR frames, two scalarized v2f FFT chains.
// R6 (resubmit; prior run died on container-acquisition infra failure):
// SOFTWARE-PIPELINE the two sets within the wave. magI/lmI are
// wave-private and same-wave DS ops execute in order, so the wave_barriers
// were unnecessary — drop them and interleave:
//   FFT(a) -> store mag(a) -> [FFT(b) || mel-gather(a)]
//   -> store mag(b) -> [DCT(a) || mel-gather(b)] -> DCT(b)
// Every LDS-gather wait slot now has independent VALU work in the same
// wave: time -> max(VALU ~1200, LDS ~1400 cyc/slot) instead of their
// alternating sum (~2345 measured). Rotation reverted (R5: conflicts UP).
// ---------------------------------------------------------------------------
#define NTHREADS 256

__global__ __launch_bounds__(NTHREADS, 5) void mfcc_kernel(
    const float* __restrict__ x, const float* __restrict__ ws,
    float* __restrict__ out) {

    __shared__ __align__(16) float magI[4][2][528];   // [wave][set][2m+frame]
    __shared__ __align__(16) float lmI[4][2][88];     // [wave][set] log-mel

    const int tid = threadIdx.x;
    const int w = tid >> 6;
    const int l = tid & 63;
    const int gw = blockIdx.x * 4 + w;
    const int fbase = 4 * gw;

    const int fid0 = fbase,     fid1 = fbase + 1;
    const int fid2 = fbase + 2, fid3 = fbase + 3;
    const int bb0 = fid0 / NF, ff0 = fid0 - bb0 * NF;
    const int bb1 = fid1 / NF, ff1 = fid1 - bb1 * NF;
    const int bb2 = fid2 / NF, ff2 = fid2 - bb2 * NF;
    const int bb3 = fid3 / NF, ff3 = fid3 - bb3 * NF;
    const float* xp0 = x + (size_t)bb0 * LL;
    const float* xp1 = x + (size_t)bb1 * LL;
    const float* xp2 = x + (size_t)bb2 * LL;
    const float* xp3 = x + (size_t)bb3 * LL;
    const int st0 = ff0 * HOP, st1 = ff1 * HOP;
    const int st2 = ff2 * HOP, st3 = ff3 * HOP;

    // ---- prefetch shared tables ----
    const float2 w1   = *(const float2*)(ws + WS_W1 + 2 * l);
    const float2 tws0 = *(const float2*)(ws + WS_STW + 0 * 128 + 2 * l);
    const float2 tws1 = *(const float2*)(ws + WS_STW + 1 * 128 + 2 * l);
    const float2 tws2 = *(const float2*)(ws + WS_STW + 2 * 128 + 2 * l);
    const float2 tws3 = *(const float2*)(ws + WS_STW + 3 * 128 + 2 * l);
    const float2 tws4 = *(const float2*)(ws + WS_STW + 4 * 128 + 2 * l);
    const int sm2 = 2 * (int)ws[WS_SM + l];

    // ---- pack: set a = frames 0/1, set b = frames 2/3; slot A: z[l + 64A] ----
    v2f a0r, a0i, a1r, a1i, a2r, a2i, a3r, a3i;
    v2f b0r, b0i, b1r, b1i, b2r, b2i, b3r, b3i;
#define PACK2(A, ZRA, ZIA, ZRB, ZIB)                                  \
    {                                                                 \
        v2f ra = splat(0.f), ia = splat(0.f);                         \
        v2f rb = splat(0.f), ib = splat(0.f);                         \
        int n2 = 2 * l + 128 * (A);                                   \
        if (n2 < WIN) {                                               \
            float2 wv = *(const float2*)(ws + WS_WINDOW + n2);        \
            int g0 = st0 + n2;                                        \
            float2 xv0 = *(const float2*)(xp0 + g0);                  \
            float xm0 = (g0 > 0) ? xp0[g0 - 1] : 0.0f;                \
            int g1 = st1 + n2;                                        \
            float2 xv1 = *(const float2*)(xp1 + g1);                  \
            float xm1 = (g1 > 0) ? xp1[g1 - 1] : 0.0f;                \
            int g2 = st2 + n2;                                        \
            float2 xv2 = *(const float2*)(xp2 + g2);                  \
            float xm2 = (g2 > 0) ? xp2[g2 - 1] : 0.0f;                \
            int g3 = st3 + n2;                                        \
            float2 xv3 = *(const float2*)(xp3 + g3);                  \
            float xm3 = (g3 > 0) ? xp3[g3 - 1] : 0.0f;                \
            ra.x = (xv0.x - 0.97f * xm0)   * wv.x;                    \
            ia.x = (xv0.y - 0.97f * xv0.x) * wv.y;                    \
            ra.y = (xv1.x - 0.97f * xm1)   * wv.x;                    \
            ia.y = (xv1.y - 0.97f * xv1.x) * wv.y;                    \
            rb.x = (xv2.x - 0.97f * xm2)   * wv.x;                    \
            ib.x = (xv2.y - 0.97f * xv2.x) * wv.y;                    \
            rb.y = (xv3.x - 0.97f * xm3)   * wv.x;                    \
            ib.y = (xv3.y - 0.97f * xv3.x) * wv.y;                    \
        }                                                             \
        ZRA = ra; ZIA = ia; ZRB = rb; ZIB = ib;                       \
    }
    PACK2(0, a0r, a0i, b0r, b0i)
    PACK2(1, a1r, a1i, b1r, b1i)
    PACK2(2, a2r, a2i, b2r, b2i)
    PACK2(3, a3r, a3i, b3r, b3i)
#undef PACK2

    // ---- in-register radix-4 over n1 (W4^1 = -i), both sets ----
#define RADIX4(Z0R, Z0I, Z1R, Z1I, Z2R, Z2I, Z3R, Z3I)                \
    {                                                                 \
        v2f t0r = Z0R + Z2R, t0i = Z0I + Z2I;                         \
        v2f t1r = Z0R - Z2R, t1i = Z0I - Z2I;                         \
        v2f t2r = Z1R + Z3R, t2i = Z1I + Z3I;                         \
        v2f t3r = Z1R - Z3R, t3i = Z1I - Z3I;                         \
        Z0R = t0r + t2r;  Z0I = t0i + t2i;                            \
        Z1R = t1r + t3i;  Z1I = t1i - t3r;                            \
        Z2R = t0r - t2r;  Z2I = t0i - t2i;                            \
        Z3R = t1r - t3i;  Z3I = t1i + t3r;                            \
    }
    RADIX4(a0r, a0i, a1r, a1i, a2r, a2i, a3r, a3i)
    RADIX4(b0r, b0i, b1r, b1i, b2r, b2i, b3r, b3i)
#undef RADIX4

    // ---- twiddle by W_256^{l*k1}, both sets ----
#define CMUL(ZR, ZI, WR, WI)                                          \
    {                                                                 \
        v2f wr = splat(WR), wi = splat(WI);                           \
        v2f tr = ZR * wr - ZI * wi;                                   \
        ZI = ZR * wi + ZI * wr;                                       \
        ZR = tr;                                                      \
    }
    {
        float w2r = w1.x * w1.x - w1.y * w1.y, w2i = 2.0f * w1.x * w1.y;
        float w3r = w2r * w1.x - w2i * w1.y,   w3i = w2r * w1.y + w2i * w1.x;
        CMUL(a1r, a1i, w1.x, w1.y)
        CMUL(b1r, b1i, w1.x, w1.y)
        CMUL(a2r, a2i, w2r,  w2i)
        CMUL(b2r, b2i, w2r,  w2i)
        CMUL(a3r, a3i, w3r,  w3i)
        CMUL(b3r, b3i, w3r,  w3i)
    }
#undef CMUL

    // ---- butterfly helpers (single reg-pair) ----
#define BF_PL(ZR, ZI, PLFN, SG, TWR, TWI)                             \
    {                                                                 \
        v2f _a, _b, ar, ai;                                           \
        PLFN(ZR, _a, _b) ar = __builtin_elementwise_fma(SG, _b, _a);  \
        PLFN(ZI, _a, _b) ai = __builtin_elementwise_fma(SG, _b, _a);  \
        ZR = ar * TWR - ai * TWI;                                     \
        ZI = ar * TWI + ai * TWR;                                     \
    }
#define BF_X(ZR, ZI, H, SG, TWR, TWI)                                 \
    {                                                                 \
        v2f pr = sfx2(ZR, H), pi = sfx2(ZI, H);                       \
        v2f ar = __builtin_elementwise_fma(SG, ZR, pr);               \
        v2f ai = __builtin_elementwise_fma(SG, ZI, pi);               \
        ZR = ar * TWR - ai * TWI;                                     \
        ZI = ar * TWI + ai * TWR;                                     \
    }
#define BF_D(ZR, ZI, CTRL, SG, TWR, TWI)                              \
    {                                                                 \
        v2f pr = dpp2<CTRL>(ZR), pi = dpp2<CTRL>(ZI);                 \
        v2f ar = __builtin_elementwise_fma(SG, ZR, pr);               \
        v2f ai = __builtin_elementwise_fma(SG, ZI, pi);               \
        ZR = ar * TWR - ai * TWI;                                     \
        ZI = ar * TWI + ai * TWR;                                     \
    }
#define BF_DLAST(ZR, ZI, CTRL, SG)                                    \
    {                                                                 \
        v2f pr = dpp2<CTRL>(ZR), pi = dpp2<CTRL>(ZI);                 \
        ZR = __builtin_elementwise_fma(SG, ZR, pr);                   \
        ZI = __builtin_elementwise_fma(SG, ZI, pi);                   \
    }

    // ---- per-set stage macros ----
#define STG32(R0,I0,R1,I1,R2,I2,R3,I3)                                \
    {                                                                 \
        v2f sg = splat((l & 32) ? -1.0f : 1.0f);                      \
        v2f twr = splat(tws0.x), twi = splat(tws0.y);                 \
        BF_PL(R0, I0, PL32, sg, twr, twi)                             \
        BF_PL(R1, I1, PL32, sg, twr, twi)                             \
        BF_PL(R2, I2, PL32, sg, twr, twi)                             \
        BF_PL(R3, I3, PL32, sg, twr, twi)                             \
    }
#define STG16(R0,I0,R1,I1,R2,I2,R3,I3)                                \
    {                                                                 \
        v2f sg = splat((l & 16) ? -1.0f : 1.0f);                      \
        v2f twr = splat(tws1.x), twi = splat(tws1.y);                 \
        BF_PL(R0, I0, PL16, sg, twr, twi)                             \
        BF_PL(R1, I1, PL16, sg, twr, twi)                             \
        BF_PL(R2, I2, PL16, sg, twr, twi)                             \
        BF_PL(R3, I3, PL16, sg, twr, twi)                             \
    }
#define STG8(R0,I0,R1,I1,R2,I2,R3,I3)                                 \
    {                                                                 \
        v2f sg = splat((l & 8) ? -1.0f : 1.0f);                       \
        v2f twr = splat(tws2.x), twi = splat(tws2.y);                 \
        BF_D(R0, I0, DPP_XOR8, sg, twr, twi)                          \
        BF_D(R1, I1, DPP_XOR8, sg, twr, twi)                          \
        BF_D(R2, I2, DPP_XOR8, sg, twr, twi)                          \
        BF_D(R3, I3, DPP_XOR8, sg, twr, twi)                          \
    }
#define STG4(R0,I0,R1,I1,R2,I2,R3,I3)                                 \
    {                                                                 \
        v2f sg = splat((l & 4) ? -1.0f : 1.0f);                       \
        v2f twr = splat(tws3.x), twi = splat(tws3.y);                 \
        BF_X(R0, I0, 4, sg, twr, twi)                                 \
        BF_X(R1, I1, 4, sg, twr, twi)                                 \
        BF_X(R2, I2, 4, sg, twr, twi)                                 \
        BF_X(R3, I3, 4, sg, twr, twi)                                 \
    }
#define STG2(R0,I0,R1,I1,R2,I2,R3,I3)                                 \
    {                                                                 \
        v2f sg = splat((l & 2) ? -1.0f : 1.0f);                       \
        v2f twr = splat(tws4.x), twi = splat(tws4.y);                 \
        BF_D(R0, I0, DPP_XOR2, sg, twr, twi)                          \
        BF_D(R1, I1, DPP_XOR2, sg, twr, twi)                          \
        BF_D(R2, I2, DPP_XOR2, sg, twr, twi)                          \
        BF_D(R3, I3, DPP_XOR2, sg, twr, twi)                          \
    }
#define STG1(R0,I0,R1,I1,R2,I2,R3,I3)                                 \
    {                                                                 \
        v2f sg = splat((l & 1) ? -1.0f : 1.0f);                       \
        BF_DLAST(R0, I0, DPP_XOR1, sg)                                \
        BF_DLAST(R1, I1, DPP_XOR1, sg)                                \
        BF_DLAST(R2, I2, DPP_XOR1, sg)                                \
        BF_DLAST(R3, I3, DPP_XOR1, sg)                                \
    }

    const int mrev = brev6(l);
    const int qsrc = brev6((64 - mrev) & 63);
    float4 uc = *(const float4*)(ws + WS_UNTC + 4 * l);
    float4 us = *(const float4*)(ws + WS_UNTS + 4 * l);

#define UNT(A, Bv, C, D, WR, WI, MG)                                  \
    {                                                                 \
        v2f Pr = A + C, Pi = Bv - D;                                  \
        v2f Qr = A - C, Qi = Bv + D;                                  \
        v2f wr = splat(WR), wi = splat(WI);                           \
        v2f Xr = Pr + wi * Qr + wr * Qi;                              \
        v2f Xi = Pi + wi * Qi - wr * Qr;                              \
        v2f s2 = __builtin_elementwise_fma(Xr, Xr, Xi * Xi);          \
        MG.x = __builtin_amdgcn_sqrtf(s2.x);                          \
        MG.y = __builtin_amdgcn_sqrtf(s2.y);                          \
    }

    // mel gather step: load weights per-jc (keeps liveness low; VMEM latency
    // hides under the interleaved FFT/DCT VALU work)
#define MEL_JC(JC, MB, MEL)                                           \
    {                                                                 \
        float4 fw = *(const float4*)(ws + WS_FBW + ((JC) * 64 + l) * 4); \
        v2f ma = *(const v2f*)((MB) + 8 * (JC) + 0);                  \
        v2f mb_ = *(const v2f*)((MB) + 8 * (JC) + 2);                 \
        v2f mc = *(const v2f*)((MB) + 8 * (JC) + 4);                  \
        v2f md = *(const v2f*)((MB) + 8 * (JC) + 6);                  \
        MEL = __builtin_elementwise_fma(splat(fw.x), ma, MEL);        \
        MEL = __builtin_elementwise_fma(splat(fw.y), mb_, MEL);       \
        MEL = __builtin_elementwise_fma(splat(fw.z), mc, MEL);        \
        MEL = __builtin_elementwise_fma(splat(fw.w), md, MEL);        \
    }

#define DCT_G(G, LM, ACC)                                             \
    {                                                                 \
        float4 m4 = m4v[G];                                           \
        float4 q0 = *(const float4*)((LM) + 8 * (G));                 \
        float4 q1 = *(const float4*)((LM) + 8 * (G) + 4);             \
        v2f p0, p1, p2, p3;                                           \
        p0.x = q0.x; p0.y = q0.y;  p1.x = q0.z; p1.y = q0.w;          \
        p2.x = q1.x; p2.y = q1.y;  p3.x = q1.z; p3.y = q1.w;          \
        ACC = __builtin_elementwise_fma(splat(m4.x), p0, ACC);        \
        ACC = __builtin_elementwise_fma(splat(m4.y), p1, ACC);        \
        ACC = __builtin_elementwise_fma(splat(m4.z), p2, ACC);        \
        ACC = __builtin_elementwise_fma(splat(m4.w), p3, ACC);        \
    }

    // ================= set a: full FFT =================
    STG32(a0r, a0i, a1r, a1i, a2r, a2i, a3r, a3i)
    STG16(a0r, a0i, a1r, a1i, a2r, a2i, a3r, a3i)
    STG8 (a0r, a0i, a1r, a1i, a2r, a2i, a3r, a3i)
    STG4 (a0r, a0i, a1r, a1i, a2r, a2i, a3r, a3i)
    STG2 (a0r, a0i, a1r, a1i, a2r, a2i, a3r, a3i)
    STG1 (a0r, a0i, a1r, a1i, a2r, a2i, a3r, a3i)

    // untangle a + store mag a (+ zero set-a tail)
    v2f m00, m01, m02, m03;
    {
        v2f p1r = sfx2(a3r, 63), p1i = sfx2(a3i, 63);
        v2f p2r = sfx2(a2r, 63), p2i = sfx2(a2i, 63);
        v2f p3r = sfx2(a1r, 63), p3i = sfx2(a1i, 63);
        v2f p0r = sfl2(a0r, qsrc), p0i = sfl2(a0i, qsrc);
        UNT(a0r, a0i, p0r, p0i, uc.x, us.x, m00)
        UNT(a1r, a1i, p1r, p1i, uc.y, us.y, m01)
        UNT(a2r, a2i, p2r, p2i, uc.z, us.z, m02)
        UNT(a3r, a3i, p3r, p3i, uc.w, us.w, m03)
    }
    {
        float* mw0 = magI[w][0];
        *(float4*)(mw0 + 8 * mrev)     = make_float4(m00.x, m00.y, m01.x, m01.y);
        *(float4*)(mw0 + 8 * mrev + 4) = make_float4(m02.x, m02.y, m03.x, m03.y);
        if (l < 4)
            *(float4*)(mw0 + 512 + 4 * l) = make_float4(0.f, 0.f, 0.f, 0.f);
    }
    // (no barrier: magI is wave-private; same-wave DS ops execute in order)

    // ================= [FFT b || mel gather a] =================
    v2f mel0 = splat(0.f);
    const float* mb0 = magI[w][0] + sm2;

    STG32(b0r, b0i, b1r, b1i, b2r, b2i, b3r, b3i)
    MEL_JC(0, mb0, mel0)
    MEL_JC(1, mb0, mel0)
    STG16(b0r, b0i, b1r, b1i, b2r, b2i, b3r, b3i)
    MEL_JC(2, mb0, mel0)
    MEL_JC(3, mb0, mel0)
    STG8 (b0r, b0i, b1r, b1i, b2r, b2i, b3r, b3i)
    MEL_JC(4, mb0, mel0)
    MEL_JC(5, mb0, mel0)
    STG4 (b0r, b0i, b1r, b1i, b2r, b2i, b3r, b3i)
    MEL_JC(6, mb0, mel0)
    MEL_JC(7, mb0, mel0)
    STG2 (b0r, b0i, b1r, b1i, b2r, b2i, b3r, b3i)
    MEL_JC(8, mb0, mel0)
    STG1 (b0r, b0i, b1r, b1i, b2r, b2i, b3r, b3i)

    // untangle b + store mag b (+ zero set-b tail)
    v2f m10, m11, m12, m13;
    {
        v2f p1r = sfx2(b3r, 63), p1i = sfx2(b3i, 63);
        v2f p2r = sfx2(b2r, 63), p2i = sfx2(b2i, 63);
        v2f p3r = sfx2(b1r, 63), p3i = sfx2(b1i, 63);
        v2f p0r = sfl2(b0r, qsrc), p0i = sfl2(b0i, qsrc);
        UNT(b0r, b0i, p0r, p0i, uc.x, us.x, m10)
        UNT(b1r, b1i, p1r, p1i, uc.y, us.y, m11)
        UNT(b2r, b2i, p2r, p2i, uc.z, us.z, m12)
        UNT(b3r, b3i, p3r, p3i, uc.w, us.w, m13)
    }
    {
        float* mw1 = magI[w][1];
        *(float4*)(mw1 + 8 * mrev)     = make_float4(m10.x, m10.y, m11.x, m11.y);
        *(float4*)(mw1 + 8 * mrev + 4) = make_float4(m12.x, m12.y, m13.x, m13.y);
        if (l < 4)
            *(float4*)(mw1 + 512 + 4 * l) = make_float4(0.f, 0.f, 0.f, 0.f);
    }

    // log a -> lm a (wave-private, no barrier)
    if (l < NMELS) {
        v2f lg0;
        lg0.x = __builtin_amdgcn_logf(mel0.x + 1e-20f) * 0.69314718055994531f;
        lg0.y = __builtin_amdgcn_logf(mel0.y + 1e-20f) * 0.69314718055994531f;
        *(v2f*)(&lmI[w][0][2 * l]) = lg0;
    }

    // fused-DCT rows (global, L1-hot; overlaps with following LDS work)
    int ii = (l < 39) ? l : 0;
    const float* mrow = ws + WS_MTT + ii * 40;
    float4 m4v[10];
    #pragma unroll
    for (int g = 0; g < 10; g++)
        m4v[g] = *(const float4*)(mrow + 4 * g);

    // ================= [DCT a || mel gather b] =================
    v2f mel1 = splat(0.f), acc0 = splat(0.f);
    const float* mb1 = magI[w][1] + sm2;
    const float* lm0 = lmI[w][0];

    MEL_JC(0, mb1, mel1)
    DCT_G(0, lm0, acc0)
    MEL_JC(1, mb1, mel1)
    DCT_G(1, lm0, acc0)
    MEL_JC(2, mb1, mel1)
    DCT_G(2, lm0, acc0)
    MEL_JC(3, mb1, mel1)
    DCT_G(3, lm0, acc0)
    MEL_JC(4, mb1, mel1)
    DCT_G(4, lm0, acc0)
    MEL_JC(5, mb1, mel1)
    DCT_G(5, lm0, acc0)
    MEL_JC(6, mb1, mel1)
    DCT_G(6, lm0, acc0)
    MEL_JC(7, mb1, mel1)
    DCT_G(7, lm0, acc0)
    MEL_JC(8, mb1, mel1)
    DCT_G(8, lm0, acc0)
    DCT_G(9, lm0, acc0)

    // log b -> lm b
    if (l < NMELS) {
        v2f lg1;
        lg1.x = __builtin_amdgcn_logf(mel1.x + 1e-20f) * 0.69314718055994531f;
        lg1.y = __builtin_amdgcn_logf(mel1.y + 1e-20f) * 0.69314718055994531f;
        *(v2f*)(&lmI[w][1][2 * l]) = lg1;
    }

    // ================= DCT b (tail) =================
    v2f acc1 = splat(0.f);
    const float* lm1 = lmI[w][1];
    DCT_G(0, lm1, acc1)
    DCT_G(1, lm1, acc1)
    DCT_G(2, lm1, acc1)
    DCT_G(3, lm1, acc1)
    DCT_G(4, lm1, acc1)
    DCT_G(5, lm1, acc1)
    DCT_G(6, lm1, acc1)
    DCT_G(7, lm1, acc1)
    DCT_G(8, lm1, acc1)
    DCT_G(9, lm1, acc1)

    if (l < 39) {
        out[(size_t)(fbase + 0) * 39 + l] = acc0.x;
        out[(size_t)(fbase + 1) * 39 + l] = acc0.y;
        out[(size_t)(fbase + 2) * 39 + l] = acc1.x;
        out[(size_t)(fbase + 3) * 39 + l] = acc1.y;
    }

#undef BF_PL
#undef BF_X
#undef BF_D
#undef BF_DLAST
#undef STG32
#undef STG16
#undef STG8
#undef STG4
#undef STG2
#undef STG1
#undef UNT
#undef MEL_JC
#undef DCT_G
}

// ---------------------------------------------------------------------------
extern "C" void kernel_launch(void* const* d_in, const int* in_sizes, int n_in,
                              void* d_out, int out_size, void* d_ws, size_t ws_size,
                              hipStream_t stream) {
    const float* x = (const float*)d_in[0];
    float* ws = (float*)d_ws;
    float* out = (float*)d_out;

    init_tables<<<64, 256, 0, stream>>>(ws);
    mfcc_kernel<<<(BB * NF) / 16, NTHREADS, 0, stream>>>(x, ws, out);
}

// Round 8
// 125.615 us; speedup vs baseline: 3.0326x; 3.0326x over previous
//
#include <hip/hip_runtime.h>
#include <cmath>

#define SRATE 16000
#define WIN   400
#define HOP   160
#define NFFT  512
#define NBIN  257          // NFFT/2+1
#define NMELS 40
#define NMFCC 13
#define BB    64
#define LL    160000
#define NF    998          // (L-WIN)/HOP + 1

#define PI_D 3.14159265358979323846

// workspace layout (floats)
#define WS_WINDOW 0                    // 400 (pre-scaled by 0.5: folds rfft-untangle factor)
#define WS_W1     400                  // 64 x float2 = 128   (W_256^l)
#define WS_STW    528                  // 6 stages x 64 x float2 = 768
#define WS_UNTC   1296                 // 64 x float4 = 256 (permuted untangle cos)
#define WS_UNTS   1552                 // 64 x float4 = 256 (permuted untangle -sin)
#define WS_SM     1808                 // 64 (filter support start bin)
#define WS_FBW    1872                 // 9 jc x 64 lanes x 4 = 2304 (mel weights)
#define WS_MTT    4176                 // 39 x 40 = 1560 (fused DCT+delta, TRANSPOSED [i][n])
#define WS_TOTAL  (WS_MTT + 1560)      // 5736 floats

using v2f = __attribute__((ext_vector_type(2))) float;

__device__ __forceinline__ int brev6(int v) { return (int)(__brev((unsigned)v) >> 26); }
__device__ __forceinline__ v2f splat(float s) { v2f r; r.x = s; r.y = s; return r; }

template<int CTRL>
__device__ __forceinline__ float dppf(float x) {
    return __int_as_float(__builtin_amdgcn_mov_dpp(__float_as_int(x), CTRL, 0xF, 0xF, true));
}
template<int CTRL>
__device__ __forceinline__ v2f dpp2(v2f v) {
    v2f r; r.x = dppf<CTRL>(v.x); r.y = dppf<CTRL>(v.y); return r;
}
__device__ __forceinline__ v2f sfx2(v2f v, int m) {
    v2f r; r.x = __shfl_xor(v.x, m, 64); r.y = __shfl_xor(v.y, m, 64); return r;
}
__device__ __forceinline__ v2f sfl2(v2f v, int src) {
    v2f r; r.x = __shfl(v.x, src, 64); r.y = __shfl(v.y, src, 64); return r;
}

// DPP controls: quad_perm xor1 = [1,0,3,2] = 0xB1; xor2 = [2,3,0,1] = 0x4E;
// row_ror:8 = 0x128 (== xor8 within each 16-lane row).
#define DPP_XOR1 0xB1
#define DPP_XOR2 0x4E
#define DPP_XOR8 0x128

// ---- gfx950 permlane swaps: xor16/xor32 butterflies on the VALU pipe ----
#if __has_builtin(__builtin_amdgcn_permlane32_swap) && __has_builtin(__builtin_amdgcn_permlane16_swap)
#define PLSWAP(FN, Z, A, Bv)                                                          \
    {                                                                                 \
        auto _r0 = FN(__float_as_int((Z).x), __float_as_int((Z).x), false, false);    \
        auto _r1 = FN(__float_as_int((Z).y), __float_as_int((Z).y), false, false);    \
        (A).x = __int_as_float(_r0[0]); (Bv).x = __int_as_float(_r0[1]);              \
        (A).y = __int_as_float(_r1[0]); (Bv).y = __int_as_float(_r1[1]);              \
    }
#define PL32(Z, A, Bv) PLSWAP(__builtin_amdgcn_permlane32_swap, Z, A, Bv)
#define PL16(Z, A, Bv) PLSWAP(__builtin_amdgcn_permlane16_swap, Z, A, Bv)
#else
#define PL32(Z, A, Bv) { (A) = sfx2((Z), 32); (Bv) = (Z); }
#define PL16(Z, A, Bv) { (A) = sfx2((Z), 16); (Bv) = (Z); }
#endif

// ---------------------------------------------------------------------------
// Init kernel (64 blocks): recompute constant tables every launch.
// ---------------------------------------------------------------------------
__global__ void init_tables(float* __restrict__ ws) {
    __shared__ double bins[NMELS + 2];
    const int tid = threadIdx.x;
    const int gid = blockIdx.x * 256 + tid;
    const int gstr = gridDim.x * 256;

    if (tid < NMELS + 2) {
        double high_mel = 2595.0 * log10(1.0 + ((double)SRATE / 2.0) / 700.0);
        double step = high_mel / (double)(NMELS + 1);
        double mel = (tid == NMELS + 1) ? high_mel : (double)tid * step;
        double hz = 700.0 * (pow(10.0, mel / 2595.0) - 1.0);
        bins[tid] = floor((double)(NFFT + 1) * hz / (double)SRATE);
    }
    __syncthreads();

    for (int i = gid; i < WIN; i += gstr)
        ws[WS_WINDOW + i] = (float)(0.5 * (0.54 - 0.46 * cos(2.0 * PI_D * (double)i / (double)WIN)));

    if (gid < 64) {
        double ang = -2.0 * PI_D * (double)gid / 256.0;
        ws[WS_W1 + 2 * gid]     = (float)cos(ang);
        ws[WS_W1 + 2 * gid + 1] = (float)sin(ang);
    }

    for (int i = gid; i < 6 * 64; i += gstr) {
        int st = i >> 6, lane = i & 63;
        int h = 32 >> st;
        double cr = 1.0, ci = 0.0;
        if (lane & h) {
            double ang = -PI_D * (double)(lane & (h - 1)) / (double)h;
            cr = cos(ang); ci = sin(ang);
        }
        ws[WS_STW + st * 128 + 2 * lane]     = (float)cr;
        ws[WS_STW + st * 128 + 2 * lane + 1] = (float)ci;
    }

    for (int i = gid; i < 256; i += gstr) {
        int lane = i >> 2, k1 = i & 3;
        int m = k1 + 4 * brev6(lane);
        double ang = 2.0 * PI_D * (double)m / 512.0;
        ws[WS_UNTC + 4 * lane + k1] = (float)cos(ang);
        ws[WS_UNTS + 4 * lane + k1] = (float)(-sin(ang));
    }

    for (int i = gid; i < 64; i += gstr)
        ws[WS_SM + i] = (i < NMELS) ? (float)bins[i] : 0.0f;

    for (int i = gid; i < 9 * 256; i += gstr) {
        int jc = i >> 8, r = (i >> 2) & 63, d = i & 3;
        int j = jc * 4 + d;
        double v = 0.0;
        if (r < NMELS) {
            double flo = bins[r], fc = bins[r + 1], fhi = bins[r + 2];
            int k = (int)flo + j;
            if (k < (int)fc)        v = ((double)k - flo) / (fc - flo);
            else if (k < (int)fhi)  v = (fhi - (double)k) / (fhi - fc);
        }
        ws[WS_FBW + i] = (float)v;
    }

    for (int t = gid; t < 39 * 40; t += gstr) {
        int i = t / 40, n = t % 40;
        auto dctf = [&](int c) -> double {
            if (c < 0 || c > 39) return 0.0;
            double sc = (c == 0) ? sqrt(1.0 / 40.0) : sqrt(2.0 / 40.0);
            return sc * cos(PI_D * (double)c * (2.0 * n + 1.0) / 80.0);
        };
        auto d1f = [&](int c) -> double {
            if (c < 1 || c > 38) return 0.0;
            return 0.5 * (dctf(c + 1) - dctf(c - 1));
        };
        double v;
        if (i < 13)       v = dctf(i);
        else if (i < 26)  v = d1f(i - 13);
        else { int c = i - 26; v = (c >= 1 && c <= 38) ? 0.5 * (d1f(c + 1) - d1f(c - 1)) : 0.0; }
        ws[WS_MTT + t] = (float)v;
    }
}

// ---------------------------------------------------------------------------
// Main kernel: one WAVE per FOUR frames, two scalarized v2f FFT chains.
// R8 = best measured configuration, assembled clean:
//   - R3 scalarized two-set structure (no arrays/loops in FFT -> no scratch)
//   - R5's m4v-loaded-after-mel (kills R3's residual 5.5MB spill)
//   - STRAIGHT mel gather order (R5's rotation raised conflicts 5.88->7.92M)
//   - wave_barriers kept (phase-separated; R6/R7 interleave spilled 792MB:
//     the allocator will not hold two overlapping phase-states in registers)
// ---------------------------------------------------------------------------
#define NTHREADS 256

__global__ __launch_bounds__(NTHREADS, 5) void mfcc_kernel(
    const float* __restrict__ x, const float* __restrict__ ws,
    float* __restrict__ out) {

    __shared__ __align__(16) float magI[4][2][528];   // [wave][set][2m+frame]
    __shared__ __align__(16) float lmI[4][2][88];     // [wave][set] log-mel

    const int tid = threadIdx.x;
    const int w = tid >> 6;
    const int l = tid & 63;
    const int gw = blockIdx.x * 4 + w;
    const int fbase = 4 * gw;

    const int fid0 = fbase,     fid1 = fbase + 1;
    const int fid2 = fbase + 2, fid3 = fbase + 3;
    const int bb0 = fid0 / NF, ff0 = fid0 - bb0 * NF;
    const int bb1 = fid1 / NF, ff1 = fid1 - bb1 * NF;
    const int bb2 = fid2 / NF, ff2 = fid2 - bb2 * NF;
    const int bb3 = fid3 / NF, ff3 = fid3 - bb3 * NF;
    const float* xp0 = x + (size_t)bb0 * LL;
    const float* xp1 = x + (size_t)bb1 * LL;
    const float* xp2 = x + (size_t)bb2 * LL;
    const float* xp3 = x + (size_t)bb3 * LL;
    const int st0 = ff0 * HOP, st1 = ff1 * HOP;
    const int st2 = ff2 * HOP, st3 = ff3 * HOP;

    // ---- prefetch shared tables ----
    const float2 w1   = *(const float2*)(ws + WS_W1 + 2 * l);
    const float2 tws0 = *(const float2*)(ws + WS_STW + 0 * 128 + 2 * l);
    const float2 tws1 = *(const float2*)(ws + WS_STW + 1 * 128 + 2 * l);
    const float2 tws2 = *(const float2*)(ws + WS_STW + 2 * 128 + 2 * l);
    const float2 tws3 = *(const float2*)(ws + WS_STW + 3 * 128 + 2 * l);
    const float2 tws4 = *(const float2*)(ws + WS_STW + 4 * 128 + 2 * l);
    const int sm2 = 2 * (int)ws[WS_SM + l];

    // ---- pack: set a = frames 0/1, set b = frames 2/3; slot A: z[l + 64A] ----
    v2f a0r, a0i, a1r, a1i, a2r, a2i, a3r, a3i;
    v2f b0r, b0i, b1r, b1i, b2r, b2i, b3r, b3i;
#define PACK2(A, ZRA, ZIA, ZRB, ZIB)                                  \
    {                                                                 \
        v2f ra = splat(0.f), ia = splat(0.f);                         \
        v2f rb = splat(0.f), ib = splat(0.f);                         \
        int n2 = 2 * l + 128 * (A);                                   \
        if (n2 < WIN) {                                               \
            float2 wv = *(const float2*)(ws + WS_WINDOW + n2);        \
            int g0 = st0 + n2;                                        \
            float2 xv0 = *(const float2*)(xp0 + g0);                  \
            float xm0 = (g0 > 0) ? xp0[g0 - 1] : 0.0f;                \
            int g1 = st1 + n2;                                        \
            float2 xv1 = *(const float2*)(xp1 + g1);                  \
            float xm1 = (g1 > 0) ? xp1[g1 - 1] : 0.0f;                \
            int g2 = st2 + n2;                                        \
            float2 xv2 = *(const float2*)(xp2 + g2);                  \
            float xm2 = (g2 > 0) ? xp2[g2 - 1] : 0.0f;                \
            int g3 = st3 + n2;                                        \
            float2 xv3 = *(const float2*)(xp3 + g3);                  \
            float xm3 = (g3 > 0) ? xp3[g3 - 1] : 0.0f;                \
            ra.x = (xv0.x - 0.97f * xm0)   * wv.x;                    \
            ia.x = (xv0.y - 0.97f * xv0.x) * wv.y;                    \
            ra.y = (xv1.x - 0.97f * xm1)   * wv.x;                    \
            ia.y = (xv1.y - 0.97f * xv1.x) * wv.y;                    \
            rb.x = (xv2.x - 0.97f * xm2)   * wv.x;                    \
            ib.x = (xv2.y - 0.97f * xv2.x) * wv.y;                    \
            rb.y = (xv3.x - 0.97f * xm3)   * wv.x;                    \
            ib.y = (xv3.y - 0.97f * xv3.x) * wv.y;                    \
        }                                                             \
        ZRA = ra; ZIA = ia; ZRB = rb; ZIB = ib;                       \
    }
    PACK2(0, a0r, a0i, b0r, b0i)
    PACK2(1, a1r, a1i, b1r, b1i)
    PACK2(2, a2r, a2i, b2r, b2i)
    PACK2(3, a3r, a3i, b3r, b3i)
#undef PACK2

    // ---- in-register radix-4 over n1 (W4^1 = -i), both sets ----
#define RADIX4(Z0R, Z0I, Z1R, Z1I, Z2R, Z2I, Z3R, Z3I)                \
    {                                                                 \
        v2f t0r = Z0R + Z2R, t0i = Z0I + Z2I;                         \
        v2f t1r = Z0R - Z2R, t1i = Z0I - Z2I;                         \
        v2f t2r = Z1R + Z3R, t2i = Z1I + Z3I;                         \
        v2f t3r = Z1R - Z3R, t3i = Z1I - Z3I;                         \
        Z0R = t0r + t2r;  Z0I = t0i + t2i;                            \
        Z1R = t1r + t3i;  Z1I = t1i - t3r;                            \
        Z2R = t0r - t2r;  Z2I = t0i - t2i;                            \
        Z3R = t1r - t3i;  Z3I = t1i + t3r;                            \
    }
    RADIX4(a0r, a0i, a1r, a1i, a2r, a2i, a3r, a3i)
    RADIX4(b0r, b0i, b1r, b1i, b2r, b2i, b3r, b3i)
#undef RADIX4

    // ---- twiddle by W_256^{l*k1}, both sets ----
#define CMUL(ZR, ZI, WR, WI)                                          \
    {                                                                 \
        v2f wr = splat(WR), wi = splat(WI);                           \
        v2f tr = ZR * wr - ZI * wi;                                   \
        ZI = ZR * wi + ZI * wr;                                       \
        ZR = tr;                                                      \
    }
    {
        float w2r = w1.x * w1.x - w1.y * w1.y, w2i = 2.0f * w1.x * w1.y;
        float w3r = w2r * w1.x - w2i * w1.y,   w3i = w2r * w1.y + w2i * w1.x;
        CMUL(a1r, a1i, w1.x, w1.y)
        CMUL(b1r, b1i, w1.x, w1.y)
        CMUL(a2r, a2i, w2r,  w2i)
        CMUL(b2r, b2i, w2r,  w2i)
        CMUL(a3r, a3i, w3r,  w3i)
        CMUL(b3r, b3i, w3r,  w3i)
    }
#undef CMUL

    // ---- 6 cross-lane DIF stages, sets interleaved, fully scalar ----
#define BF_PL(ZR, ZI, PLFN, SG, TWR, TWI)                             \
    {                                                                 \
        v2f _a, _b, ar, ai;                                           \
        PLFN(ZR, _a, _b) ar = __builtin_elementwise_fma(SG, _b, _a);  \
        PLFN(ZI, _a, _b) ai = __builtin_elementwise_fma(SG, _b, _a);  \
        ZR = ar * TWR - ai * TWI;                                     \
        ZI = ar * TWI + ai * TWR;                                     \
    }
#define BF_X(ZR, ZI, H, SG, TWR, TWI)                                 \
    {                                                                 \
        v2f pr = sfx2(ZR, H), pi = sfx2(ZI, H);                       \
        v2f ar = __builtin_elementwise_fma(SG, ZR, pr);               \
        v2f ai = __builtin_elementwise_fma(SG, ZI, pi);               \
        ZR = ar * TWR - ai * TWI;                                     \
        ZI = ar * TWI + ai * TWR;                                     \
    }
#define BF_D(ZR, ZI, CTRL, SG, TWR, TWI)                              \
    {                                                                 \
        v2f pr = dpp2<CTRL>(ZR), pi = dpp2<CTRL>(ZI);                 \
        v2f ar = __builtin_elementwise_fma(SG, ZR, pr);               \
        v2f ai = __builtin_elementwise_fma(SG, ZI, pi);               \
        ZR = ar * TWR - ai * TWI;                                     \
        ZI = ar * TWI + ai * TWR;                                     \
    }
#define BF_DLAST(ZR, ZI, CTRL, SG)                                    \
    {                                                                 \
        v2f pr = dpp2<CTRL>(ZR), pi = dpp2<CTRL>(ZI);                 \
        ZR = __builtin_elementwise_fma(SG, ZR, pr);                   \
        ZI = __builtin_elementwise_fma(SG, ZI, pi);                   \
    }

    // stage xor32 (permlane32_swap)
    {
        v2f sg = splat((l & 32) ? -1.0f : 1.0f);
        v2f twr = splat(tws0.x), twi = splat(tws0.y);
        BF_PL(a0r, a0i, PL32, sg, twr, twi)
        BF_PL(b0r, b0i, PL32, sg, twr, twi)
        BF_PL(a1r, a1i, PL32, sg, twr, twi)
        BF_PL(b1r, b1i, PL32, sg, twr, twi)
        BF_PL(a2r, a2i, PL32, sg, twr, twi)
        BF_PL(b2r, b2i, PL32, sg, twr, twi)
        BF_PL(a3r, a3i, PL32, sg, twr, twi)
        BF_PL(b3r, b3i, PL32, sg, twr, twi)
    }
    // stage xor16 (permlane16_swap)
    {
        v2f sg = splat((l & 16) ? -1.0f : 1.0f);
        v2f twr = splat(tws1.x), twi = splat(tws1.y);
        BF_PL(a0r, a0i, PL16, sg, twr, twi)
        BF_PL(b0r, b0i, PL16, sg, twr, twi)
        BF_PL(a1r, a1i, PL16, sg, twr, twi)
        BF_PL(b1r, b1i, PL16, sg, twr, twi)
        BF_PL(a2r, a2i, PL16, sg, twr, twi)
        BF_PL(b2r, b2i, PL16, sg, twr, twi)
        BF_PL(a3r, a3i, PL16, sg, twr, twi)
        BF_PL(b3r, b3i, PL16, sg, twr, twi)
    }
    // stage xor8 (DPP row_ror:8)
    {
        v2f sg = splat((l & 8) ? -1.0f : 1.0f);
        v2f twr = splat(tws2.x), twi = splat(tws2.y);
        BF_D(a0r, a0i, DPP_XOR8, sg, twr, twi)
        BF_D(b0r, b0i, DPP_XOR8, sg, twr, twi)
        BF_D(a1r, a1i, DPP_XOR8, sg, twr, twi)
        BF_D(b1r, b1i, DPP_XOR8, sg, twr, twi)
        BF_D(a2r, a2i, DPP_XOR8, sg, twr, twi)
        BF_D(b2r, b2i, DPP_XOR8, sg, twr, twi)
        BF_D(a3r, a3i, DPP_XOR8, sg, twr, twi)
        BF_D(b3r, b3i, DPP_XOR8, sg, twr, twi)
    }
    // stage xor4 (DS shuffle)
    {
        v2f sg = splat((l & 4) ? -1.0f : 1.0f);
        v2f twr = splat(tws3.x), twi = splat(tws3.y);
        BF_X(a0r, a0i, 4, sg, twr, twi)
        BF_X(b0r, b0i, 4, sg, twr, twi)
        BF_X(a1r, a1i, 4, sg, twr, twi)
        BF_X(b1r, b1i, 4, sg, twr, twi)
        BF_X(a2r, a2i, 4, sg, twr, twi)
        BF_X(b2r, b2i, 4, sg, twr, twi)
        BF_X(a3r, a3i, 4, sg, twr, twi)
        BF_X(b3r, b3i, 4, sg, twr, twi)
    }
    // stage xor2 (DPP quad_perm)
    {
        v2f sg = splat((l & 2) ? -1.0f : 1.0f);
        v2f twr = splat(tws4.x), twi = splat(tws4.y);
        BF_D(a0r, a0i, DPP_XOR2, sg, twr, twi)
        BF_D(b0r, b0i, DPP_XOR2, sg, twr, twi)
        BF_D(a1r, a1i, DPP_XOR2, sg, twr, twi)
        BF_D(b1r, b1i, DPP_XOR2, sg, twr, twi)
        BF_D(a2r, a2i, DPP_XOR2, sg, twr, twi)
        BF_D(b2r, b2i, DPP_XOR2, sg, twr, twi)
        BF_D(a3r, a3i, DPP_XOR2, sg, twr, twi)
        BF_D(b3r, b3i, DPP_XOR2, sg, twr, twi)
    }
    // stage xor1 (DPP quad_perm, last: no twiddle)
    {
        v2f sg = splat((l & 1) ? -1.0f : 1.0f);
        BF_DLAST(a0r, a0i, DPP_XOR1, sg)
        BF_DLAST(b0r, b0i, DPP_XOR1, sg)
        BF_DLAST(a1r, a1i, DPP_XOR1, sg)
        BF_DLAST(b1r, b1i, DPP_XOR1, sg)
        BF_DLAST(a2r, a2i, DPP_XOR1, sg)
        BF_DLAST(b2r, b2i, DPP_XOR1, sg)
        BF_DLAST(a3r, a3i, DPP_XOR1, sg)
        BF_DLAST(b3r, b3i, DPP_XOR1, sg)
    }
#undef BF_PL
#undef BF_X
#undef BF_D
#undef BF_DLAST

    // lane l slot k1 holds Z[m], m = k1 + 4*bitrev6(l)  (all scaled by 0.5)

    const int mrev = brev6(l);
    const int qsrc = brev6((64 - mrev) & 63);
    float4 uc = *(const float4*)(ws + WS_UNTC + 4 * l);
    float4 us = *(const float4*)(ws + WS_UNTS + 4 * l);

    // ---- rfft untangle + |X|, both sets, scalarized ----
    v2f m00, m01, m02, m03, m10, m11, m12, m13;
#define UNT(A, Bv, C, D, WR, WI, MG)                                  \
    {                                                                 \
        v2f Pr = A + C, Pi = Bv - D;                                  \
        v2f Qr = A - C, Qi = Bv + D;                                  \
        v2f wr = splat(WR), wi = splat(WI);                           \
        v2f Xr = Pr + wi * Qr + wr * Qi;                              \
        v2f Xi = Pi + wi * Qi - wr * Qr;                              \
        v2f s2 = __builtin_elementwise_fma(Xr, Xr, Xi * Xi);          \
        MG.x = __builtin_amdgcn_sqrtf(s2.x);                          \
        MG.y = __builtin_amdgcn_sqrtf(s2.y);                          \
    }
    {
        v2f p1r = sfx2(a3r, 63), p1i = sfx2(a3i, 63);
        v2f p2r = sfx2(a2r, 63), p2i = sfx2(a2i, 63);
        v2f p3r = sfx2(a1r, 63), p3i = sfx2(a1i, 63);
        v2f p0r = sfl2(a0r, qsrc), p0i = sfl2(a0i, qsrc);
        UNT(a0r, a0i, p0r, p0i, uc.x, us.x, m00)
        UNT(a1r, a1i, p1r, p1i, uc.y, us.y, m01)
        UNT(a2r, a2i, p2r, p2i, uc.z, us.z, m02)
        UNT(a3r, a3i, p3r, p3i, uc.w, us.w, m03)
    }
    {
        v2f p1r = sfx2(b3r, 63), p1i = sfx2(b3i, 63);
        v2f p2r = sfx2(b2r, 63), p2i = sfx2(b2i, 63);
        v2f p3r = sfx2(b1r, 63), p3i = sfx2(b1i, 63);
        v2f p0r = sfl2(b0r, qsrc), p0i = sfl2(b0i, qsrc);
        UNT(b0r, b0i, p0r, p0i, uc.x, us.x, m10)
        UNT(b1r, b1i, p1r, p1i, uc.y, us.y, m11)
        UNT(b2r, b2i, p2r, p2i, uc.z, us.z, m12)
        UNT(b3r, b3i, p3r, p3i, uc.w, us.w, m13)
    }
#undef UNT

    // ---- store magnitudes interleaved: two b128 stores per set ----
    {
        float* mw0 = magI[w][0];
        *(float4*)(mw0 + 8 * mrev)     = make_float4(m00.x, m00.y, m01.x, m01.y);
        *(float4*)(mw0 + 8 * mrev + 4) = make_float4(m02.x, m02.y, m03.x, m03.y);
        float* mw1 = magI[w][1];
        *(float4*)(mw1 + 8 * mrev)     = make_float4(m10.x, m10.y, m11.x, m11.y);
        *(float4*)(mw1 + 8 * mrev + 4) = make_float4(m12.x, m12.y, m13.x, m13.y);
    }
    if (l < 8) {   // zero tail bins 256..263 of both sets (weights are 0 there)
        *(float4*)(&magI[w][l >> 2][512 + 4 * (l & 3)]) = make_float4(0.f, 0.f, 0.f, 0.f);
    }

    // ---- prefetch ALL mel weights (straight order; shared by both sets) ----
    float4 fwv[9];
    #pragma unroll
    for (int jc = 0; jc < 9; jc++)
        fwv[jc] = *(const float4*)(ws + WS_FBW + (jc * 64 + l) * 4);

    __builtin_amdgcn_wave_barrier();

    // ---- mel: lane l = filter l; both sets share weight registers ----
    v2f mel0 = splat(0.f), mel1 = splat(0.f);
    {
        const float* mb0 = magI[w][0] + sm2;
        const float* mb1 = magI[w][1] + sm2;
        #pragma unroll
        for (int jc = 0; jc < 9; jc++) {
            float4 fw = fwv[jc];
            v2f a0 = *(const v2f*)(mb0 + 8 * jc + 0);
            v2f c0 = *(const v2f*)(mb0 + 8 * jc + 2);
            v2f e0 = *(const v2f*)(mb0 + 8 * jc + 4);
            v2f g0 = *(const v2f*)(mb0 + 8 * jc + 6);
            v2f a1 = *(const v2f*)(mb1 + 8 * jc + 0);
            v2f c1 = *(const v2f*)(mb1 + 8 * jc + 2);
            v2f e1 = *(const v2f*)(mb1 + 8 * jc + 4);
            v2f g1 = *(const v2f*)(mb1 + 8 * jc + 6);
            mel0 = __builtin_elementwise_fma(splat(fw.x), a0, mel0);
            mel0 = __builtin_elementwise_fma(splat(fw.y), c0, mel0);
            mel0 = __builtin_elementwise_fma(splat(fw.z), e0, mel0);
            mel0 = __builtin_elementwise_fma(splat(fw.w), g0, mel0);
            mel1 = __builtin_elementwise_fma(splat(fw.x), a1, mel1);
            mel1 = __builtin_elementwise_fma(splat(fw.y), c1, mel1);
            mel1 = __builtin_elementwise_fma(splat(fw.z), e1, mel1);
            mel1 = __builtin_elementwise_fma(splat(fw.w), g1, mel1);
        }
    }

    // ---- log, stage interleaved lm ----
    if (l < NMELS) {
        v2f lg0, lg1;
        lg0.x = __builtin_amdgcn_logf(mel0.x + 1e-20f) * 0.69314718055994531f;
        lg0.y = __builtin_amdgcn_logf(mel0.y + 1e-20f) * 0.69314718055994531f;
        lg1.x = __builtin_amdgcn_logf(mel1.x + 1e-20f) * 0.69314718055994531f;
        lg1.y = __builtin_amdgcn_logf(mel1.y + 1e-20f) * 0.69314718055994531f;
        *(v2f*)(&lmI[w][0][2 * l]) = lg0;
        *(v2f*)(&lmI[w][1][2 * l]) = lg1;
    }

    // ---- load fused-DCT rows AFTER mel (fwv dead -> no spill) ----
    int ii = (l < 39) ? l : 0;
    const float* mrow = ws + WS_MTT + ii * 40;
    float4 m4v[10];
    #pragma unroll
    for (int g = 0; g < 10; g++)
        m4v[g] = *(const float4*)(mrow + 4 * g);

    __builtin_amdgcn_wave_barrier();

    // ---- fused DCT+deltas matvec, LDS broadcast reads (conflict-free) ----
    v2f acc0 = splat(0.f), acc1 = splat(0.f);
    {
        const float* lm0 = lmI[w][0];
        const float* lm1 = lmI[w][1];
        #pragma unroll
        for (int g = 0; g < 10; g++) {
            float4 m4 = m4v[g];
            float4 q00 = *(const float4*)(lm0 + 8 * g);
            float4 q01 = *(const float4*)(lm0 + 8 * g + 4);
            float4 q10 = *(const float4*)(lm1 + 8 * g);
            float4 q11 = *(const float4*)(lm1 + 8 * g + 4);
            v2f p0, p1, p2, p3;
            p0.x = q00.x; p0.y = q00.y;  p1.x = q00.z; p1.y = q00.w;
            p2.x = q01.x; p2.y = q01.y;  p3.x = q01.z; p3.y = q01.w;
            acc0 = __builtin_elementwise_fma(splat(m4.x), p0, acc0);
            acc0 = __builtin_elementwise_fma(splat(m4.y), p1, acc0);
            acc0 = __builtin_elementwise_fma(splat(m4.z), p2, acc0);
            acc0 = __builtin_elementwise_fma(splat(m4.w), p3, acc0);
            p0.x = q10.x; p0.y = q10.y;  p1.x = q10.z; p1.y = q10.w;
            p2.x = q11.x; p2.y = q11.y;  p3.x = q11.z; p3.y = q11.w;
            acc1 = __builtin_elementwise_fma(splat(m4.x), p0, acc1);
            acc1 = __builtin_elementwise_fma(splat(m4.y), p1, acc1);
            acc1 = __builtin_elementwise_fma(splat(m4.z), p2, acc1);
            acc1 = __builtin_elementwise_fma(splat(m4.w), p3, acc1);
        }
    }
    if (l < 39) {
        out[(size_t)(fbase + 0) * 39 + l] = acc0.x;
        out[(size_t)(fbase + 1) * 39 + l] = acc0.y;
        out[(size_t)(fbase + 2) * 39 + l] = acc1.x;
        out[(size_t)(fbase + 3) * 39 + l] = acc1.y;
    }
}

// ---------------------------------------------------------------------------
extern "C" void kernel_launch(void* const* d_in, const int* in_sizes, int n_in,
                              void* d_out, int out_size, void* d_ws, size_t ws_size,
                              hipStream_t stream) {
    const float* x = (const float*)d_in[0];
    float* ws = (float*)d_ws;
    float* out = (float*)d_out;

    init_tables<<<64, 256, 0, stream>>>(ws);
    mfcc_kernel<<<(BB * NF) / 16, NTHREADS, 0, stream>>>(x, ws, out);
}

// Round 9
// 120.425 us; speedup vs baseline: 3.1633x; 1.0431x over previous
//
#include <hip/hip_runtime.h>
#include <cmath>

#define SRATE 16000
#define WIN   400
#define HOP   160
#define NFFT  512
#define NBIN  257          // NFFT/2+1
#define NMELS 40
#define NMFCC 13
#define BB    64
#define LL    160000
#define NF    998          // (L-WIN)/HOP + 1

#define PI_D 3.14159265358979323846

// workspace layout (floats)
#define WS_WINDOW 0                    // 400 (pre-scaled by 0.5: folds rfft-untangle factor)
#define WS_W1     400                  // 64 x float2 = 128   (W_256^l)
#define WS_STW    528                  // 6 stages x 64 x float2 = 768
#define WS_UNTC   1296                 // 64 x float4 = 256 (permuted untangle cos)
#define WS_UNTS   1552                 // 64 x float4 = 256 (permuted untangle -sin)
#define WS_SM     1808                 // 64 (filter support start bin)
#define WS_FBW    1872                 // 9 jc x 64 lanes x 4 = 2304 (mel weights)
#define WS_MTT    4176                 // 39 x 40 = 1560 (fused DCT+delta, TRANSPOSED [i][n])
#define WS_TOTAL  (WS_MTT + 1560)      // 5736 floats

using v2f = __attribute__((ext_vector_type(2))) float;

__device__ __forceinline__ int brev6(int v) { return (int)(__brev((unsigned)v) >> 26); }
__device__ __forceinline__ v2f splat(float s) { v2f r; r.x = s; r.y = s; return r; }

template<int CTRL>
__device__ __forceinline__ float dppf(float x) {
    return __int_as_float(__builtin_amdgcn_mov_dpp(__float_as_int(x), CTRL, 0xF, 0xF, true));
}
template<int CTRL>
__device__ __forceinline__ v2f dpp2(v2f v) {
    v2f r; r.x = dppf<CTRL>(v.x); r.y = dppf<CTRL>(v.y); return r;
}
__device__ __forceinline__ v2f sfx2(v2f v, int m) {
    v2f r; r.x = __shfl_xor(v.x, m, 64); r.y = __shfl_xor(v.y, m, 64); return r;
}
__device__ __forceinline__ v2f sfl2(v2f v, int src) {
    v2f r; r.x = __shfl(v.x, src, 64); r.y = __shfl(v.y, src, 64); return r;
}

// DPP controls: quad_perm xor1 = [1,0,3,2] = 0xB1; xor2 = [2,3,0,1] = 0x4E;
// row_ror:8 = 0x128 (== xor8 within each 16-lane row).
#define DPP_XOR1 0xB1
#define DPP_XOR2 0x4E
#define DPP_XOR8 0x128

// ---- gfx950 permlane swaps: xor16/xor32 butterflies on the VALU pipe ----
#if __has_builtin(__builtin_amdgcn_permlane32_swap) && __has_builtin(__builtin_amdgcn_permlane16_swap)
#define PLSWAP(FN, Z, A, Bv)                                                          \
    {                                                                                 \
        auto _r0 = FN(__float_as_int((Z).x), __float_as_int((Z).x), false, false);    \
        auto _r1 = FN(__float_as_int((Z).y), __float_as_int((Z).y), false, false);    \
        (A).x = __int_as_float(_r0[0]); (Bv).x = __int_as_float(_r0[1]);              \
        (A).y = __int_as_float(_r1[0]); (Bv).y = __int_as_float(_r1[1]);              \
    }
#define PL32(Z, A, Bv) PLSWAP(__builtin_amdgcn_permlane32_swap, Z, A, Bv)
#define PL16(Z, A, Bv) PLSWAP(__builtin_amdgcn_permlane16_swap, Z, A, Bv)
#else
#define PL32(Z, A, Bv) { (A) = sfx2((Z), 32); (Bv) = (Z); }
#define PL16(Z, A, Bv) { (A) = sfx2((Z), 16); (Bv) = (Z); }
#endif

// ---------------------------------------------------------------------------
// Init kernel (64 blocks): recompute constant tables every launch.
// ---------------------------------------------------------------------------
__global__ void init_tables(float* __restrict__ ws) {
    __shared__ double bins[NMELS + 2];
    const int tid = threadIdx.x;
    const int gid = blockIdx.x * 256 + tid;
    const int gstr = gridDim.x * 256;

    if (tid < NMELS + 2) {
        double high_mel = 2595.0 * log10(1.0 + ((double)SRATE / 2.0) / 700.0);
        double step = high_mel / (double)(NMELS + 1);
        double mel = (tid == NMELS + 1) ? high_mel : (double)tid * step;
        double hz = 700.0 * (pow(10.0, mel / 2595.0) - 1.0);
        bins[tid] = floor((double)(NFFT + 1) * hz / (double)SRATE);
    }
    __syncthreads();

    for (int i = gid; i < WIN; i += gstr)
        ws[WS_WINDOW + i] = (float)(0.5 * (0.54 - 0.46 * cos(2.0 * PI_D * (double)i / (double)WIN)));

    if (gid < 64) {
        double ang = -2.0 * PI_D * (double)gid / 256.0;
        ws[WS_W1 + 2 * gid]     = (float)cos(ang);
        ws[WS_W1 + 2 * gid + 1] = (float)sin(ang);
    }

    for (int i = gid; i < 6 * 64; i += gstr) {
        int st = i >> 6, lane = i & 63;
        int h = 32 >> st;
        double cr = 1.0, ci = 0.0;
        if (lane & h) {
            double ang = -PI_D * (double)(lane & (h - 1)) / (double)h;
            cr = cos(ang); ci = sin(ang);
        }
        ws[WS_STW + st * 128 + 2 * lane]     = (float)cr;
        ws[WS_STW + st * 128 + 2 * lane + 1] = (float)ci;
    }

    for (int i = gid; i < 256; i += gstr) {
        int lane = i >> 2, k1 = i & 3;
        int m = k1 + 4 * brev6(lane);
        double ang = 2.0 * PI_D * (double)m / 512.0;
        ws[WS_UNTC + 4 * lane + k1] = (float)cos(ang);
        ws[WS_UNTS + 4 * lane + k1] = (float)(-sin(ang));
    }

    for (int i = gid; i < 64; i += gstr)
        ws[WS_SM + i] = (i < NMELS) ? (float)bins[i] : 0.0f;

    for (int i = gid; i < 9 * 256; i += gstr) {
        int jc = i >> 8, r = (i >> 2) & 63, d = i & 3;
        int j = jc * 4 + d;
        double v = 0.0;
        if (r < NMELS) {
            double flo = bins[r], fc = bins[r + 1], fhi = bins[r + 2];
            int k = (int)flo + j;
            if (k < (int)fc)        v = ((double)k - flo) / (fc - flo);
            else if (k < (int)fhi)  v = (fhi - (double)k) / (fhi - fc);
        }
        ws[WS_FBW + i] = (float)v;
    }

    for (int t = gid; t < 39 * 40; t += gstr) {
        int i = t / 40, n = t % 40;
        auto dctf = [&](int c) -> double {
            if (c < 0 || c > 39) return 0.0;
            double sc = (c == 0) ? sqrt(1.0 / 40.0) : sqrt(2.0 / 40.0);
            return sc * cos(PI_D * (double)c * (2.0 * n + 1.0) / 80.0);
        };
        auto d1f = [&](int c) -> double {
            if (c < 1 || c > 38) return 0.0;
            return 0.5 * (dctf(c + 1) - dctf(c - 1));
        };
        double v;
        if (i < 13)       v = dctf(i);
        else if (i < 26)  v = d1f(i - 13);
        else { int c = i - 26; v = (c >= 1 && c <= 38) ? 0.5 * (d1f(c + 1) - d1f(c - 1)) : 0.0; }
        ws[WS_MTT + t] = (float)v;
    }
}

// ---------------------------------------------------------------------------
// Main kernel: ONE WAVE PER BLOCK (64 threads), four frames per wave, two
// scalarized v2f FFT chains. R9 changes vs R8:
//   - block = 1 wave: no __syncthreads anywhere, so 4-wave blocks only
//     constrained the scheduler (place/retire granularity, 42% occupancy).
//     LDS/block 19968 -> 4928 B; 15968 independent blocks.
//   - mel weights loaded per-jc inside the loop (R0-proven no-spill form;
//     the fwv[9] block prefetch tipped the allocator into 5.8MB scratch).
//   - m4v still loaded after mel (R3's early load spilled).
// ---------------------------------------------------------------------------
#define NTHREADS 64

__global__ __launch_bounds__(NTHREADS, 6) void mfcc_kernel(
    const float* __restrict__ x, const float* __restrict__ ws,
    float* __restrict__ out) {

    __shared__ __align__(16) float magI[2][528];   // [set][2m+frame]
    __shared__ __align__(16) float lmI[2][88];     // [set] log-mel

    const int l = threadIdx.x;
    const int gw = blockIdx.x;
    const int fbase = 4 * gw;

    const int fid0 = fbase,     fid1 = fbase + 1;
    const int fid2 = fbase + 2, fid3 = fbase + 3;
    const int bb0 = fid0 / NF, ff0 = fid0 - bb0 * NF;
    const int bb1 = fid1 / NF, ff1 = fid1 - bb1 * NF;
    const int bb2 = fid2 / NF, ff2 = fid2 - bb2 * NF;
    const int bb3 = fid3 / NF, ff3 = fid3 - bb3 * NF;
    const float* xp0 = x + (size_t)bb0 * LL;
    const float* xp1 = x + (size_t)bb1 * LL;
    const float* xp2 = x + (size_t)bb2 * LL;
    const float* xp3 = x + (size_t)bb3 * LL;
    const int st0 = ff0 * HOP, st1 = ff1 * HOP;
    const int st2 = ff2 * HOP, st3 = ff3 * HOP;

    // ---- prefetch shared tables ----
    const float2 w1   = *(const float2*)(ws + WS_W1 + 2 * l);
    const float2 tws0 = *(const float2*)(ws + WS_STW + 0 * 128 + 2 * l);
    const float2 tws1 = *(const float2*)(ws + WS_STW + 1 * 128 + 2 * l);
    const float2 tws2 = *(const float2*)(ws + WS_STW + 2 * 128 + 2 * l);
    const float2 tws3 = *(const float2*)(ws + WS_STW + 3 * 128 + 2 * l);
    const float2 tws4 = *(const float2*)(ws + WS_STW + 4 * 128 + 2 * l);
    const int sm2 = 2 * (int)ws[WS_SM + l];

    // ---- pack: set a = frames 0/1, set b = frames 2/3; slot A: z[l + 64A] ----
    v2f a0r, a0i, a1r, a1i, a2r, a2i, a3r, a3i;
    v2f b0r, b0i, b1r, b1i, b2r, b2i, b3r, b3i;
#define PACK2(A, ZRA, ZIA, ZRB, ZIB)                                  \
    {                                                                 \
        v2f ra = splat(0.f), ia = splat(0.f);                         \
        v2f rb = splat(0.f), ib = splat(0.f);                         \
        int n2 = 2 * l + 128 * (A);                                   \
        if (n2 < WIN) {                                               \
            float2 wv = *(const float2*)(ws + WS_WINDOW + n2);        \
            int g0 = st0 + n2;                                        \
            float2 xv0 = *(const float2*)(xp0 + g0);                  \
            float xm0 = (g0 > 0) ? xp0[g0 - 1] : 0.0f;                \
            int g1 = st1 + n2;                                        \
            float2 xv1 = *(const float2*)(xp1 + g1);                  \
            float xm1 = (g1 > 0) ? xp1[g1 - 1] : 0.0f;                \
            int g2 = st2 + n2;                                        \
            float2 xv2 = *(const float2*)(xp2 + g2);                  \
            float xm2 = (g2 > 0) ? xp2[g2 - 1] : 0.0f;                \
            int g3 = st3 + n2;                                        \
            float2 xv3 = *(const float2*)(xp3 + g3);                  \
            float xm3 = (g3 > 0) ? xp3[g3 - 1] : 0.0f;                \
            ra.x = (xv0.x - 0.97f * xm0)   * wv.x;                    \
            ia.x = (xv0.y - 0.97f * xv0.x) * wv.y;                    \
            ra.y = (xv1.x - 0.97f * xm1)   * wv.x;                    \
            ia.y = (xv1.y - 0.97f * xv1.x) * wv.y;                    \
            rb.x = (xv2.x - 0.97f * xm2)   * wv.x;                    \
            ib.x = (xv2.y - 0.97f * xv2.x) * wv.y;                    \
            rb.y = (xv3.x - 0.97f * xm3)   * wv.x;                    \
            ib.y = (xv3.y - 0.97f * xv3.x) * wv.y;                    \
        }                                                             \
        ZRA = ra; ZIA = ia; ZRB = rb; ZIB = ib;                       \
    }
    PACK2(0, a0r, a0i, b0r, b0i)
    PACK2(1, a1r, a1i, b1r, b1i)
    PACK2(2, a2r, a2i, b2r, b2i)
    PACK2(3, a3r, a3i, b3r, b3i)
#undef PACK2

    // ---- in-register radix-4 over n1 (W4^1 = -i), both sets ----
#define RADIX4(Z0R, Z0I, Z1R, Z1I, Z2R, Z2I, Z3R, Z3I)                \
    {                                                                 \
        v2f t0r = Z0R + Z2R, t0i = Z0I + Z2I;                         \
        v2f t1r = Z0R - Z2R, t1i = Z0I - Z2I;                         \
        v2f t2r = Z1R + Z3R, t2i = Z1I + Z3I;                         \
        v2f t3r = Z1R - Z3R, t3i = Z1I - Z3I;                         \
        Z0R = t0r + t2r;  Z0I = t0i + t2i;                            \
        Z1R = t1r + t3i;  Z1I = t1i - t3r;                            \
        Z2R = t0r - t2r;  Z2I = t0i - t2i;                            \
        Z3R = t1r - t3i;  Z3I = t1i + t3r;                            \
    }
    RADIX4(a0r, a0i, a1r, a1i, a2r, a2i, a3r, a3i)
    RADIX4(b0r, b0i, b1r, b1i, b2r, b2i, b3r, b3i)
#undef RADIX4

    // ---- twiddle by W_256^{l*k1}, both sets ----
#define CMUL(ZR, ZI, WR, WI)                                          \
    {                                                                 \
        v2f wr = splat(WR), wi = splat(WI);                           \
        v2f tr = ZR * wr - ZI * wi;                                   \
        ZI = ZR * wi + ZI * wr;                                       \
        ZR = tr;                                                      \
    }
    {
        float w2r = w1.x * w1.x - w1.y * w1.y, w2i = 2.0f * w1.x * w1.y;
        float w3r = w2r * w1.x - w2i * w1.y,   w3i = w2r * w1.y + w2i * w1.x;
        CMUL(a1r, a1i, w1.x, w1.y)
        CMUL(b1r, b1i, w1.x, w1.y)
        CMUL(a2r, a2i, w2r,  w2i)
        CMUL(b2r, b2i, w2r,  w2i)
        CMUL(a3r, a3i, w3r,  w3i)
        CMUL(b3r, b3i, w3r,  w3i)
    }
#undef CMUL

    // ---- 6 cross-lane DIF stages, sets interleaved, fully scalar ----
#define BF_PL(ZR, ZI, PLFN, SG, TWR, TWI)                             \
    {                                                                 \
        v2f _a, _b, ar, ai;                                           \
        PLFN(ZR, _a, _b) ar = __builtin_elementwise_fma(SG, _b, _a);  \
        PLFN(ZI, _a, _b) ai = __builtin_elementwise_fma(SG, _b, _a);  \
        ZR = ar * TWR - ai * TWI;                                     \
        ZI = ar * TWI + ai * TWR;                                     \
    }
#define BF_X(ZR, ZI, H, SG, TWR, TWI)                                 \
    {                                                                 \
        v2f pr = sfx2(ZR, H), pi = sfx2(ZI, H);                       \
        v2f ar = __builtin_elementwise_fma(SG, ZR, pr);               \
        v2f ai = __builtin_elementwise_fma(SG, ZI, pi);               \
        ZR = ar * TWR - ai * TWI;                                     \
        ZI = ar * TWI + ai * TWR;                                     \
    }
#define BF_D(ZR, ZI, CTRL, SG, TWR, TWI)                              \
    {                                                                 \
        v2f pr = dpp2<CTRL>(ZR), pi = dpp2<CTRL>(ZI);                 \
        v2f ar = __builtin_elementwise_fma(SG, ZR, pr);               \
        v2f ai = __builtin_elementwise_fma(SG, ZI, pi);               \
        ZR = ar * TWR - ai * TWI;                                     \
        ZI = ar * TWI + ai * TWR;                                     \
    }
#define BF_DLAST(ZR, ZI, CTRL, SG)                                    \
    {                                                                 \
        v2f pr = dpp2<CTRL>(ZR), pi = dpp2<CTRL>(ZI);                 \
        ZR = __builtin_elementwise_fma(SG, ZR, pr);                   \
        ZI = __builtin_elementwise_fma(SG, ZI, pi);                   \
    }

    // stage xor32 (permlane32_swap)
    {
        v2f sg = splat((l & 32) ? -1.0f : 1.0f);
        v2f twr = splat(tws0.x), twi = splat(tws0.y);
        BF_PL(a0r, a0i, PL32, sg, twr, twi)
        BF_PL(b0r, b0i, PL32, sg, twr, twi)
        BF_PL(a1r, a1i, PL32, sg, twr, twi)
        BF_PL(b1r, b1i, PL32, sg, twr, twi)
        BF_PL(a2r, a2i, PL32, sg, twr, twi)
        BF_PL(b2r, b2i, PL32, sg, twr, twi)
        BF_PL(a3r, a3i, PL32, sg, twr, twi)
        BF_PL(b3r, b3i, PL32, sg, twr, twi)
    }
    // stage xor16 (permlane16_swap)
    {
        v2f sg = splat((l & 16) ? -1.0f : 1.0f);
        v2f twr = splat(tws1.x), twi = splat(tws1.y);
        BF_PL(a0r, a0i, PL16, sg, twr, twi)
        BF_PL(b0r, b0i, PL16, sg, twr, twi)
        BF_PL(a1r, a1i, PL16, sg, twr, twi)
        BF_PL(b1r, b1i, PL16, sg, twr, twi)
        BF_PL(a2r, a2i, PL16, sg, twr, twi)
        BF_PL(b2r, b2i, PL16, sg, twr, twi)
        BF_PL(a3r, a3i, PL16, sg, twr, twi)
        BF_PL(b3r, b3i, PL16, sg, twr, twi)
    }
    // stage xor8 (DPP row_ror:8)
    {
        v2f sg = splat((l & 8) ? -1.0f : 1.0f);
        v2f twr = splat(tws2.x), twi = splat(tws2.y);
        BF_D(a0r, a0i, DPP_XOR8, sg, twr, twi)
        BF_D(b0r, b0i, DPP_XOR8, sg, twr, twi)
        BF_D(a1r, a1i, DPP_XOR8, sg, twr, twi)
        BF_D(b1r, b1i, DPP_XOR8, sg, twr, twi)
        BF_D(a2r, a2i, DPP_XOR8, sg, twr, twi)
        BF_D(b2r, b2i, DPP_XOR8, sg, twr, twi)
        BF_D(a3r, a3i, DPP_XOR8, sg, twr, twi)
        BF_D(b3r, b3i, DPP_XOR8, sg, twr, twi)
    }
    // stage xor4 (DS shuffle)
    {
        v2f sg = splat((l & 4) ? -1.0f : 1.0f);
        v2f twr = splat(tws3.x), twi = splat(tws3.y);
        BF_X(a0r, a0i, 4, sg, twr, twi)
        BF_X(b0r, b0i, 4, sg, twr, twi)
        BF_X(a1r, a1i, 4, sg, twr, twi)
        BF_X(b1r, b1i, 4, sg, twr, twi)
        BF_X(a2r, a2i, 4, sg, twr, twi)
        BF_X(b2r, b2i, 4, sg, twr, twi)
        BF_X(a3r, a3i, 4, sg, twr, twi)
        BF_X(b3r, b3i, 4, sg, twr, twi)
    }
    // stage xor2 (DPP quad_perm)
    {
        v2f sg = splat((l & 2) ? -1.0f : 1.0f);
        v2f twr = splat(tws4.x), twi = splat(tws4.y);
        BF_D(a0r, a0i, DPP_XOR2, sg, twr, twi)
        BF_D(b0r, b0i, DPP_XOR2, sg, twr, twi)
        BF_D(a1r, a1i, DPP_XOR2, sg, twr, twi)
        BF_D(b1r, b1i, DPP_XOR2, sg, twr, twi)
        BF_D(a2r, a2i, DPP_XOR2, sg, twr, twi)
        BF_D(b2r, b2i, DPP_XOR2, sg, twr, twi)
        BF_D(a3r, a3i, DPP_XOR2, sg, twr, twi)
        BF_D(b3r, b3i, DPP_XOR2, sg, twr, twi)
    }
    // stage xor1 (DPP quad_perm, last: no twiddle)
    {
        v2f sg = splat((l & 1) ? -1.0f : 1.0f);
        BF_DLAST(a0r, a0i, DPP_XOR1, sg)
        BF_DLAST(b0r, b0i, DPP_XOR1, sg)
        BF_DLAST(a1r, a1i, DPP_XOR1, sg)
        BF_DLAST(b1r, b1i, DPP_XOR1, sg)
        BF_DLAST(a2r, a2i, DPP_XOR1, sg)
        BF_DLAST(b2r, b2i, DPP_XOR1, sg)
        BF_DLAST(a3r, a3i, DPP_XOR1, sg)
        BF_DLAST(b3r, b3i, DPP_XOR1, sg)
    }
#undef BF_PL
#undef BF_X
#undef BF_D
#undef BF_DLAST

    // lane l slot k1 holds Z[m], m = k1 + 4*bitrev6(l)  (all scaled by 0.5)

    const int mrev = brev6(l);
    const int qsrc = brev6((64 - mrev) & 63);
    float4 uc = *(const float4*)(ws + WS_UNTC + 4 * l);
    float4 us = *(const float4*)(ws + WS_UNTS + 4 * l);

    // ---- rfft untangle + |X|, both sets, scalarized ----
    v2f m00, m01, m02, m03, m10, m11, m12, m13;
#define UNT(A, Bv, C, D, WR, WI, MG)                                  \
    {                                                                 \
        v2f Pr = A + C, Pi = Bv - D;                                  \
        v2f Qr = A - C, Qi = Bv + D;                                  \
        v2f wr = splat(WR), wi = splat(WI);                           \
        v2f Xr = Pr + wi * Qr + wr * Qi;                              \
        v2f Xi = Pi + wi * Qi - wr * Qr;                              \
        v2f s2 = __builtin_elementwise_fma(Xr, Xr, Xi * Xi);          \
        MG.x = __builtin_amdgcn_sqrtf(s2.x);                          \
        MG.y = __builtin_amdgcn_sqrtf(s2.y);                          \
    }
    {
        v2f p1r = sfx2(a3r, 63), p1i = sfx2(a3i, 63);
        v2f p2r = sfx2(a2r, 63), p2i = sfx2(a2i, 63);
        v2f p3r = sfx2(a1r, 63), p3i = sfx2(a1i, 63);
        v2f p0r = sfl2(a0r, qsrc), p0i = sfl2(a0i, qsrc);
        UNT(a0r, a0i, p0r, p0i, uc.x, us.x, m00)
        UNT(a1r, a1i, p1r, p1i, uc.y, us.y, m01)
        UNT(a2r, a2i, p2r, p2i, uc.z, us.z, m02)
        UNT(a3r, a3i, p3r, p3i, uc.w, us.w, m03)
    }
    {
        v2f p1r = sfx2(b3r, 63), p1i = sfx2(b3i, 63);
        v2f p2r = sfx2(b2r, 63), p2i = sfx2(b2i, 63);
        v2f p3r = sfx2(b1r, 63), p3i = sfx2(b1i, 63);
        v2f p0r = sfl2(b0r, qsrc), p0i = sfl2(b0i, qsrc);
        UNT(b0r, b0i, p0r, p0i, uc.x, us.x, m10)
        UNT(b1r, b1i, p1r, p1i, uc.y, us.y, m11)
        UNT(b2r, b2i, p2r, p2i, uc.z, us.z, m12)
        UNT(b3r, b3i, p3r, p3i, uc.w, us.w, m13)
    }
#undef UNT

    // ---- store magnitudes interleaved: two b128 stores per set ----
    {
        float* mw0 = magI[0];
        *(float4*)(mw0 + 8 * mrev)     = make_float4(m00.x, m00.y, m01.x, m01.y);
        *(float4*)(mw0 + 8 * mrev + 4) = make_float4(m02.x, m02.y, m03.x, m03.y);
        float* mw1 = magI[1];
        *(float4*)(mw1 + 8 * mrev)     = make_float4(m10.x, m10.y, m11.x, m11.y);
        *(float4*)(mw1 + 8 * mrev + 4) = make_float4(m12.x, m12.y, m13.x, m13.y);
    }
    if (l < 8) {   // zero tail bins 256..263 of both sets (weights are 0 there)
        *(float4*)(&magI[l >> 2][512 + 4 * (l & 3)]) = make_float4(0.f, 0.f, 0.f, 0.f);
    }

    __builtin_amdgcn_wave_barrier();

    // ---- mel: lane l = filter l; fw loaded per-jc (R0-proven no-spill) ----
    v2f mel0 = splat(0.f), mel1 = splat(0.f);
    {
        const float* mb0 = magI[0] + sm2;
        const float* mb1 = magI[1] + sm2;
        #pragma unroll
        for (int jc = 0; jc < 9; jc++) {
            float4 fw = *(const float4*)(ws + WS_FBW + (jc * 64 + l) * 4);
            v2f a0 = *(const v2f*)(mb0 + 8 * jc + 0);
            v2f c0 = *(const v2f*)(mb0 + 8 * jc + 2);
            v2f e0 = *(const v2f*)(mb0 + 8 * jc + 4);
            v2f g0 = *(const v2f*)(mb0 + 8 * jc + 6);
            v2f a1 = *(const v2f*)(mb1 + 8 * jc + 0);
            v2f c1 = *(const v2f*)(mb1 + 8 * jc + 2);
            v2f e1 = *(const v2f*)(mb1 + 8 * jc + 4);
            v2f g1 = *(const v2f*)(mb1 + 8 * jc + 6);
            mel0 = __builtin_elementwise_fma(splat(fw.x), a0, mel0);
            mel0 = __builtin_elementwise_fma(splat(fw.y), c0, mel0);
            mel0 = __builtin_elementwise_fma(splat(fw.z), e0, mel0);
            mel0 = __builtin_elementwise_fma(splat(fw.w), g0, mel0);
            mel1 = __builtin_elementwise_fma(splat(fw.x), a1, mel1);
            mel1 = __builtin_elementwise_fma(splat(fw.y), c1, mel1);
            mel1 = __builtin_elementwise_fma(splat(fw.z), e1, mel1);
            mel1 = __builtin_elementwise_fma(splat(fw.w), g1, mel1);
        }
    }

    // ---- log, stage interleaved lm ----
    if (l < NMELS) {
        v2f lg0, lg1;
        lg0.x = __builtin_amdgcn_logf(mel0.x + 1e-20f) * 0.69314718055994531f;
        lg0.y = __builtin_amdgcn_logf(mel0.y + 1e-20f) * 0.69314718055994531f;
        lg1.x = __builtin_amdgcn_logf(mel1.x + 1e-20f) * 0.69314718055994531f;
        lg1.y = __builtin_amdgcn_logf(mel1.y + 1e-20f) * 0.69314718055994531f;
        *(v2f*)(&lmI[0][2 * l]) = lg0;
        *(v2f*)(&lmI[1][2 * l]) = lg1;
    }

    // ---- load fused-DCT rows AFTER mel (early load spilled in R3) ----
    int ii = (l < 39) ? l : 0;
    const float* mrow = ws + WS_MTT + ii * 40;
    float4 m4v[10];
    #pragma unroll
    for (int g = 0; g < 10; g++)
        m4v[g] = *(const float4*)(mrow + 4 * g);

    __builtin_amdgcn_wave_barrier();

    // ---- fused DCT+deltas matvec, LDS broadcast reads (conflict-free) ----
    v2f acc0 = splat(0.f), acc1 = splat(0.f);
    {
        const float* lm0 = lmI[0];
        const float* lm1 = lmI[1];
        #pragma unroll
        for (int g = 0; g < 10; g++) {
            float4 m4 = m4v[g];
            float4 q00 = *(const float4*)(lm0 + 8 * g);
            float4 q01 = *(const float4*)(lm0 + 8 * g + 4);
            float4 q10 = *(const float4*)(lm1 + 8 * g);
            float4 q11 = *(const float4*)(lm1 + 8 * g + 4);
            v2f p0, p1, p2, p3;
            p0.x = q00.x; p0.y = q00.y;  p1.x = q00.z; p1.y = q00.w;
            p2.x = q01.x; p2.y = q01.y;  p3.x = q01.z; p3.y = q01.w;
            acc0 = __builtin_elementwise_fma(splat(m4.x), p0, acc0);
            acc0 = __builtin_elementwise_fma(splat(m4.y), p1, acc0);
            acc0 = __builtin_elementwise_fma(splat(m4.z), p2, acc0);
            acc0 = __builtin_elementwise_fma(splat(m4.w), p3, acc0);
            p0.x = q10.x; p0.y = q10.y;  p1.x = q10.z; p1.y = q10.w;
            p2.x = q11.x; p2.y = q11.y;  p3.x = q11.z; p3.y = q11.w;
            acc1 = __builtin_elementwise_fma(splat(m4.x), p0, acc1);
            acc1 = __builtin_elementwise_fma(splat(m4.y), p1, acc1);
            acc1 = __builtin_elementwise_fma(splat(m4.z), p2, acc1);
            acc1 = __builtin_elementwise_fma(splat(m4.w), p3, acc1);
        }
    }
    if (l < 39) {
        out[(size_t)(fbase + 0) * 39 + l] = acc0.x;
        out[(size_t)(fbase + 1) * 39 + l] = acc0.y;
        out[(size_t)(fbase + 2) * 39 + l] = acc1.x;
        out[(size_t)(fbase + 3) * 39 + l] = acc1.y;
    }
}

// ---------------------------------------------------------------------------
extern "C" void kernel_launch(void* const* d_in, const int* in_sizes, int n_in,
                              void* d_out, int out_size, void* d_ws, size_t ws_size,
                              hipStream_t stream) {
    const float* x = (const float*)d_in[0];
    float* ws = (float*)d_ws;
    float* out = (float*)d_out;

    init_tables<<<64, 256, 0, stream>>>(ws);
    mfcc_kernel<<<(BB * NF) / 4, NTHREADS, 0, stream>>>(x, ws, out);
}